// Round 11
// baseline (407.648 us; speedup 1.0000x reference)
//
#include <hip/hip_runtime.h>

typedef __bf16 bf16_t;
typedef __bf16 bf16x8 __attribute__((ext_vector_type(8)));
typedef __bf16 bf16x4 __attribute__((ext_vector_type(4)));
typedef float  floatx4 __attribute__((ext_vector_type(4)));

__device__ __forceinline__ void gload_lds16(const bf16_t* g, bf16_t* l) {
    __builtin_amdgcn_global_load_lds(
        (const __attribute__((address_space(1))) void*)g,
        (__attribute__((address_space(3))) void*)l,
        16, 0, 0);
}

// Inline-asm ds_read_b128 (opaque to the waitcnt pass; proven correct on HW
// r7-r10). Completion enforced manually: per-wave lgkmcnt(0) +
// sched_barrier(0) before the consuming MFMA (rule 18).
__device__ __forceinline__ bf16x8 ds_read_b128f(const bf16_t* l) {
    bf16x8 r;
    asm volatile("ds_read_b128 %0, %1"
        : "=v"(r)
        : "v"((const __attribute__((address_space(3))) bf16_t*)l));
    return r;
}

// ---------------------------------------------------------------------------
// Grid barrier for a 256-block / 1-block-per-CU kernel (co-residency is
// HW-guaranteed: 128 KiB LDS caps 1 block/CU and grid == #CUs, so all 256
// blocks are resident -> spin is safe). Counters are zeroed every replay by
// a captured hipMemsetAsync node. Coherence across non-coherent XCD L2s:
//  release: __threadfence() (wb L2) before agent-scope atomicAdd arrival;
//  acquire: agent-scope atomic poll + __threadfence() (inv) before reads.
// Bounded spin: worst case breaks out (-> wrong result, caught by test),
// never hangs the container.
// ---------------------------------------------------------------------------
__device__ __forceinline__ void gridbar(unsigned* ctr) {
    __syncthreads();
    if (threadIdx.x == 0) {
        __threadfence();   // write back this XCD's L2 (phase outputs)
        __hip_atomic_fetch_add(ctr, 1u, __ATOMIC_ACQ_REL,
                               __HIP_MEMORY_SCOPE_AGENT);
        int spins = 0;
        while (__hip_atomic_load(ctr, __ATOMIC_RELAXED,
                                 __HIP_MEMORY_SCOPE_AGENT) < 256u) {
            __builtin_amdgcn_s_sleep(16);
            if (++spins > (1 << 21)) break;   // anti-hang escape (~1 s)
        }
    }
    __syncthreads();
    __threadfence();       // acquire: invalidate stale L1/L2 before reads
}

// ---------------------------------------------------------------------------
// 256xBN 8-phase GEMM core (r7 structure, verbatim; measured+passing on HW
// rounds 7-10 at ~785 TF). C = A * B^T, NT, row-major, K-contiguous.
// Phase: {asm ds_reads(cur frags) | STAGE 1 region | [vmcnt(VM)]} bar#1
//        lgkmcnt(0) sched_barrier(0) setprio(1) MFMAs setprio(0) bar#2.
// 512 threads = 8 waves (2M x 4N); wave tile 128 x (BN/4); BK=64.
// BN=256: LDS 128 KiB, vmcnt(6). BN=128: LDS 96 KiB, vmcnt(4).
// MAP decodes the flat 256-block index h (XCD = h % 8):
//  MAP 1: 8x8x4 (Sc, PV). MAP 2: 4x64 (V^T). MAP 3: 32x8 natural (QK).
// MODE 1: plain bf16 C store                       (V^T direct, BN=128)
// MODE 2: bf16 C = exp(acc*scale) + atomic rowsums (Sc, BN=256)
// MODE 3: float C = acc / rowsums[row], rowsums read via agent-scope
//         atomic loads (stale-L2 immunity inside the mega-kernel)
// MODE 5: split store: bn<1024 -> C (Q), else C2 (K)          (BN=256)
// ---------------------------------------------------------------------------
template <int MODE, int BN, int MAP, typename OutT>
__device__ __forceinline__ void gemm_core(
    int h,
    const bf16_t* A, int lda, size_t batchA,
    const bf16_t* B, int ldb, size_t batchB,
    OutT* C, int ldc, size_t batchC,
    bf16_t* C2,
    float* rowsums, int batchR,
    int K, float scale, bf16_t* smem)
{
    constexpr int NJ   = BN / 64;
    constexpr int WCB  = BN / 4;
    constexpr int BGL  = BN / 128;
    constexpr int AREG = 8192;
    constexpr int BREG = BN * 32;
    constexpr int BOFF = 2 * AREG;
    constexpr int BUFS = BOFF + 2 * BREG;
    constexpr int VM   = 2 + 2 * BGL;

    int bxL, byL, bzL;
    if constexpr (MAP == 1) {
        const int k = h & 7, s = h >> 3;
        bzL = k >> 1; bxL = ((k & 1) << 2) | (s & 3); byL = s >> 2;
    } else if constexpr (MAP == 2) {
        const int k = h & 7, s = h >> 3;
        bzL = 0; bxL = s >> 3; byL = (k << 3) | (s & 7);
    } else {  // MAP == 3: logical 32x8, x fastest
        bxL = h & 31; byL = h >> 5; bzL = 0;
    }

    A += (size_t)bzL * batchA;
    B += (size_t)bzL * batchB;

    const int tid  = threadIdx.x;
    const int wid  = tid >> 6;
    const int lane = tid & 63;
    const int wr   = wid >> 2;
    const int wc   = wid & 3;
    const int lr   = lane & 15;

    const int bm = bxL * 256;
    const int bn = byL * BN;

    const bf16_t* At = A + (size_t)bm * lda;
    const bf16_t* Bt = B + (size_t)bn * ldb;

    // staging: 64 B region rows; LDS dest linear, source chunk pre-swizzled
    // (slot s of row r holds chunk s^((r>>1)&3)).
    const int    c8 = (((lane & 3) ^ ((lane >> 3) & 3)) << 3);
    const size_t ga = (size_t)(wid * 16 + (lane >> 2)) * lda + c8;
    const size_t gb = (size_t)(wid * 16 + (lane >> 2)) * ldb + c8;

    const int slotoff = (((lane >> 4) ^ ((lr >> 1) & 3)) << 3);

    const int NT = K >> 6;

    floatx4 acc[8][NJ] = {};
    bf16x8 af[4], bq[NJ];

#define RBASE(sbuf, sreg)                                                     \
    ((sbuf) * BUFS + ((sreg) < 2 ? (sreg) * AREG : BOFF + ((sreg) - 2) * BREG))

#define STAGE(sbuf, sreg, tile) do {                                          \
    bf16_t* _l = smem + RBASE(sbuf, sreg) + (wid << 9);                       \
    const size_t _k = (size_t)(tile) * 64 + ((sreg) & 1) * 32;                \
    if ((sreg) >= 2) {                                                        \
        gload_lds16(Bt + _k + gb, _l);                                        \
        if (BGL == 2)                                                         \
            gload_lds16(Bt + _k + gb + (size_t)128 * ldb, _l + 4096);         \
    } else {                                                                  \
        gload_lds16(At + _k + ga, _l);                                        \
        gload_lds16(At + _k + ga + (size_t)128 * lda, _l + 4096);             \
    }                                                                         \
} while (0)

#define PHASE(buf, kk, mh, RDB, sbuf, sreg, stile, DOVM) do {                 \
    if (RDB) {                                                                \
        _Pragma("unroll")                                                     \
        for (int j = 0; j < NJ; ++j)                                          \
            bq[j] = ds_read_b128f(&smem[(buf) * BUFS + BOFF + (kk) * BREG +   \
                        ((wc * WCB + j * 16 + lr) << 5) + slotoff]);          \
    }                                                                         \
    _Pragma("unroll")                                                         \
    for (int i = 0; i < 4; ++i)                                               \
        af[i] = ds_read_b128f(&smem[(buf) * BUFS + (kk) * AREG +              \
                    ((wr * 128 + (mh) * 64 + i * 16 + lr) << 5) + slotoff]);  \
    STAGE(sbuf, sreg, stile);                                                 \
    if (DOVM) {                                                               \
        if constexpr (VM == 6) asm volatile("s_waitcnt vmcnt(6)" ::: "memory");\
        else                   asm volatile("s_waitcnt vmcnt(4)" ::: "memory");\
    }                                                                         \
    __builtin_amdgcn_s_barrier();                                             \
    asm volatile("s_waitcnt lgkmcnt(0)" ::: "memory");                        \
    __builtin_amdgcn_sched_barrier(0);                                        \
    __builtin_amdgcn_s_setprio(1);                                            \
    _Pragma("unroll")                                                         \
    for (int i = 0; i < 4; ++i) {                                             \
        _Pragma("unroll")                                                     \
        for (int j = 0; j < NJ; ++j)                                          \
            acc[(mh) * 4 + i][j] = __builtin_amdgcn_mfma_f32_16x16x32_bf16(   \
                bq[j], af[i], acc[(mh) * 4 + i][j], 0, 0, 0);                 \
    }                                                                         \
    __builtin_amdgcn_s_setprio(0);                                            \
    __builtin_amdgcn_s_barrier();                                             \
} while (0)

    // Prologue: buf0 fully + buf1 {Bk0,Ak0,Bk1}; vmcnt(VM) leaves exactly
    // buf1's trio outstanding => all of buf0 landed before ph1's reads.
    STAGE(0, 2, 0); STAGE(0, 0, 0); STAGE(0, 3, 0); STAGE(0, 1, 0);
    STAGE(1, 2, 1); STAGE(1, 0, 1); STAGE(1, 3, 1);
    if constexpr (VM == 6) asm volatile("s_waitcnt vmcnt(6)" ::: "memory");
    else                   asm volatile("s_waitcnt vmcnt(4)" ::: "memory");
    __builtin_amdgcn_s_barrier();

    for (int kt = 0; kt < NT; kt += 2) {
        int t1 = kt + 1;
        int t2 = kt + 2; if (t2 >= NT) t2 -= NT;   // tail wrap: redundant
        int t3 = kt + 3; if (t3 >= NT) t3 -= NT;   // stages, never consumed
        PHASE(0, 0, 0, 1,  1, 1, t1, 0);
        PHASE(0, 0, 1, 0,  0, 2, t2, 0);
        PHASE(0, 1, 0, 1,  0, 0, t2, 0);
        PHASE(0, 1, 1, 0,  0, 3, t2, 1);
        PHASE(1, 0, 0, 1,  0, 1, t2, 0);
        PHASE(1, 0, 1, 0,  1, 2, t3, 0);
        PHASE(1, 1, 0, 1,  1, 0, t3, 0);
        PHASE(1, 1, 1, 0,  1, 3, t3, 1);
    }
    asm volatile("s_waitcnt vmcnt(0)" ::: "memory");

#undef PHASE
#undef STAGE
#undef RBASE

    // D layout: m = lane&15 (arg1 = af), n = (lane>>4)*4 + reg (arg0 = bq)
    const int cfix = lane & 15;
    const int creg = (lane >> 4) << 2;

    if constexpr (MODE == 1) {
        OutT* Cz = C + (size_t)bzL * batchC;
        #pragma unroll
        for (int mi = 0; mi < 8; ++mi) {
            size_t row = (size_t)(bm + wr * 128 + mi * 16 + cfix);
            #pragma unroll
            for (int j = 0; j < NJ; ++j) {
                int col = bn + wc * WCB + j * 16 + creg;
                bf16x4 v;
                #pragma unroll
                for (int r = 0; r < 4; ++r) v[r] = (bf16_t)acc[mi][j][r];
                *(bf16x4*)&Cz[row * (size_t)ldc + col] = v;
            }
        }
    } else if constexpr (MODE == 5) {
        bf16_t* dst = (bn < 1024) ? (bf16_t*)C : C2;
        const int cb = bn & 1023;
        #pragma unroll
        for (int mi = 0; mi < 8; ++mi) {
            size_t row = (size_t)(bm + wr * 128 + mi * 16 + cfix);
            #pragma unroll
            for (int j = 0; j < NJ; ++j) {
                int col = cb + wc * WCB + j * 16 + creg;
                bf16x4 v;
                #pragma unroll
                for (int r = 0; r < 4; ++r) v[r] = (bf16_t)acc[mi][j][r];
                *(bf16x4*)&dst[row * (size_t)ldc + col] = v;
            }
        }
    } else if constexpr (MODE == 2) {
        OutT* Cz = C + (size_t)bzL * batchC;
        float* sums = rowsums + (size_t)bzL * batchR;
        float rs[8] = {};
        #pragma unroll
        for (int mi = 0; mi < 8; ++mi) {
            size_t row = (size_t)(bm + wr * 128 + mi * 16 + cfix);
            #pragma unroll
            for (int j = 0; j < NJ; ++j) {
                int col = bn + wc * WCB + j * 16 + creg;
                bf16x4 v;
                #pragma unroll
                for (int r = 0; r < 4; ++r) {
                    v[r] = (bf16_t)__expf(acc[mi][j][r] * scale);
                    rs[mi] += (float)v[r];
                }
                *(bf16x4*)&Cz[row * (size_t)ldc + col] = v;
            }
        }
        #pragma unroll
        for (int mi = 0; mi < 8; ++mi) {
            rs[mi] += __shfl_xor(rs[mi], 16);
            rs[mi] += __shfl_xor(rs[mi], 32);
        }
        if (lane < 16) {
            #pragma unroll
            for (int mi = 0; mi < 8; ++mi)
                atomicAdd(&sums[bm + wr * 128 + mi * 16 + lane], rs[mi]);
        }
    } else {  // MODE == 3: PV with normalization (atomic sums reads)
        OutT* Cz = C + (size_t)bzL * batchC;
        const float* sums = rowsums + (size_t)bzL * batchR;
        #pragma unroll
        for (int mi = 0; mi < 8; ++mi) {
            int rloc = bm + wr * 128 + mi * 16 + cfix;
            float sv = __hip_atomic_load(&sums[rloc], __ATOMIC_RELAXED,
                                         __HIP_MEMORY_SCOPE_AGENT);
            float rinv = 1.0f / sv;
            size_t row = (size_t)rloc;
            #pragma unroll
            for (int j = 0; j < NJ; ++j) {
                int col = bn + wc * WCB + j * 16 + creg;
                floatx4 v;
                #pragma unroll
                for (int r = 0; r < 4; ++r) v[r] = acc[mi][j][r] * rinv;
                *(floatx4*)&Cz[row * (size_t)ldc + col] = v;
            }
        }
    }
}

// ---------------------------------------------------------------------------
// MEGA-KERNEL: all 5 stages as phases of ONE 256-block dispatch, separated
// by gridbar (device-scope). Rationale (r0-r10): each GEMM dispatch is
// pinned at ~785 TF regardless of schedule; the remaining ~60-70 us of
// total time is inter-dispatch overhead (launch gaps + per-kernel L2
// flush boundaries + queue sync). One dispatch removes 4 of those
// boundaries; the in-kernel barriers pay only the unavoidable L2
// writeback. Coherence audit: every inter-phase buffer is written exactly
// once and first-touched by readers post-fence; sums (zeroed P0, atomic-
// added P3, read P4) is read via agent-scope atomic loads.
// Phases (each logical grid is exactly 256 blocks):
//  P0 cvt: fp32->bf16 X,Wq,Wk,Wv (grid-stride) + zero sums
//  P1 QK:  X*(Wq||Wk)^T split-stored -> Qb,Kb   (MODE 5, BN=256, MAP 3)
//  P2 V^T: Wv*X^T -> Vt                          (MODE 1, BN=128, MAP 2)
//  P3 Sc:  exp(Q K^T/32) + rowsums               (MODE 2, BN=256, MAP 1)
//  P4 PV:  (Sc V)/rowsum -> out                  (MODE 3, BN=128, MAP 1)
// ---------------------------------------------------------------------------
__global__ __launch_bounds__(512, 2) void mega_attn(
    const float* __restrict__ X, const float* __restrict__ Wq,
    const float* __restrict__ Wk, const float* __restrict__ Wv,
    bf16_t* Xb, bf16_t* Wqb, bf16_t* Wkb, bf16_t* Wvb,
    bf16_t* Qb, bf16_t* Kb, bf16_t* Vt, bf16_t* Sc,
    float* sums, float* out, unsigned* bar,
    int nX4, int nW4)
{
    extern __shared__ __align__(16) bf16_t smem[];
    const int h   = blockIdx.x;
    const int tid = threadIdx.x;
    const int S = 2048, D = 1024, M = 8192;

    // ---- P0: convert + zero sums -------------------------------------
    {
        const int gtid = h * 512 + tid;            // 0..131071
        const int tot4 = nX4 + 3 * nW4;
        for (int i = gtid; i < tot4; i += 131072) {
            const float* src; bf16_t* dst; int idx;
            if (i < nX4) { src = X; dst = Xb; idx = i; }
            else {
                int j = i - nX4;
                int w = j / nW4;
                idx = j - w * nW4;
                src = (w == 0) ? Wq : (w == 1) ? Wk : Wv;
                dst = (w == 0) ? Wqb : (w == 1) ? Wkb : Wvb;
            }
            float4 v = ((const float4*)src)[idx];
            bf16x4 o;
            o[0] = (bf16_t)v.x; o[1] = (bf16_t)v.y;
            o[2] = (bf16_t)v.z; o[3] = (bf16_t)v.w;
            *(bf16x4*)(dst + (size_t)idx * 4) = o;
        }
        if (gtid < M) sums[gtid] = 0.f;
    }
    gridbar(bar + 0);

    // ---- P1: QK (Wqb||Wkb adjacent => B is [2048][1024]) -------------
    gemm_core<5, 256, 3, bf16_t>(h, Xb, D, 0, Wqb, D, 0,
                                 Qb, D, 0, Kb, nullptr, 0, D, 1.0f, smem);
    gridbar(bar + 16);

    // ---- P2: V^T direct: Vt[d][s] = sum_e Wv[d][e] X[s][e] -----------
    gemm_core<1, 128, 2, bf16_t>(h, Wvb, D, 0, Xb, D, 0,
                                 Vt, M, 0, nullptr, nullptr, 0, D, 1.0f, smem);
    gridbar(bar + 32);

    // ---- P3: Sc = exp(Q K^T / 32) + rowsums --------------------------
    gemm_core<2, 256, 1, bf16_t>(h, Qb, D, (size_t)S * D, Kb, D, (size_t)S * D,
                                 Sc, S, (size_t)S * S, nullptr,
                                 sums, S, D, 0.03125f, smem);
    gridbar(bar + 48);

    // ---- P4: out = (Sc V) / rowsum -----------------------------------
    gemm_core<3, 128, 1, float>(h, Sc, S, (size_t)S * S, Vt, M, (size_t)S,
                                out, D, (size_t)S * D, nullptr,
                                sums, S, S, 1.0f, smem);
}

extern "C" void kernel_launch(void* const* d_in, const int* in_sizes, int n_in,
                              void* d_out, int out_size, void* d_ws, size_t ws_size,
                              hipStream_t stream)
{
    (void)in_sizes; (void)n_in; (void)out_size; (void)ws_size;
    const float* X  = (const float*)d_in[0];
    const float* Wq = (const float*)d_in[1];
    const float* Wk = (const float*)d_in[2];
    const float* Wv = (const float*)d_in[3];
    float* out = (float*)d_out;

    const int Bb = 4, S = 2048, D = 1024;
    const int M = Bb * S;  // 8192

    char* ws = (char*)d_ws;
    size_t off = 0;
    auto carve = [&](size_t bytes) -> char* {
        char* p = ws + off;
        off += (bytes + 255) & ~(size_t)255;
        return p;
    };
    // Contiguity invariant: Wqb,Wkb adjacent (Wkb == Wqb + D*D): the fused
    // QK phase uses Wqb as a [2048][1024] B-matrix (Wq||Wk rows).
    bf16_t* Xb  = (bf16_t*)carve((size_t)M * D * 2);
    bf16_t* Wqb = (bf16_t*)carve((size_t)D * D * 2);
    bf16_t* Wkb = (bf16_t*)carve((size_t)D * D * 2);
    bf16_t* Wvb = (bf16_t*)carve((size_t)D * D * 2);
    bf16_t* Qb  = (bf16_t*)carve((size_t)M * D * 2);
    bf16_t* Kb  = (bf16_t*)carve((size_t)M * D * 2);
    bf16_t* Vt  = (bf16_t*)carve((size_t)D * M * 2);   // V^T: D x M
    bf16_t* Sc  = (bf16_t*)carve((size_t)Bb * S * S * 2);
    float*  sums = (float*)carve((size_t)M * 4);
    unsigned* bar = (unsigned*)carve(256);             // 4 ctrs, 64B apart

    static bool s_attr = false;
    if (!s_attr) {
        (void)hipFuncSetAttribute(
            reinterpret_cast<const void*>(&mega_attn),
            hipFuncAttributeMaxDynamicSharedMemorySize, 131072);
        s_attr = true;
    }

    // Zero barrier counters every execution (captured as a memset node).
    (void)hipMemsetAsync(bar, 0, 256, stream);

    const int nX4 = M * D / 4, nW4 = D * D / 4;
    mega_attn<<<dim3(256, 1, 1), 512, 131072, stream>>>(
        X, Wq, Wk, Wv, Xb, Wqb, Wkb, Wvb, Qb, Kb, Vt, Sc,
        sums, out, bar, nX4, nW4);
}